// Round 5
// baseline (484.787 us; speedup 1.0000x reference)
//
#include <hip/hip_runtime.h>
#include <hip/hip_bf16.h>

// Problem constants (fixed by reference setup_inputs)
#define NNODES 50000
#define NEDGES 800000
#define DIN    512
#define FOUT   256

typedef __attribute__((ext_vector_type(8))) short short8;
typedef __attribute__((ext_vector_type(4))) float f32x4;
typedef __attribute__((ext_vector_type(4))) unsigned int u32x4;
typedef __attribute__((ext_vector_type(4))) unsigned short usv4;
typedef __attribute__((ext_vector_type(8))) unsigned short usv8;

static __device__ __forceinline__ unsigned short f2bf(float f) {
    unsigned int u = __float_as_uint(f);
    u += 0x7FFF + ((u >> 16) & 1);   // round-to-nearest-even
    return (unsigned short)(u >> 16);
}
static __device__ __forceinline__ float bf2f(unsigned short h) {
    return __uint_as_float(((unsigned int)h) << 16);
}

// ---------------- prep: W^T convert (blocks 0..511) + edge hist (512..) -----
__global__ void prep_kernel(const float* __restrict__ W, unsigned short* __restrict__ Wt,
                            const int* __restrict__ row, int* __restrict__ cnt) {
    int b = blockIdx.x;
    if (b < 512) {
        int o = b * 256 + threadIdx.x;           // 131072 total
        int n = o >> 9, k = o & 511;
        Wt[o] = f2bf(W[k * FOUT + n]);
    } else {
        int e = (b - 512) * 256 + threadIdx.x;
        if (e < NEDGES) atomicAdd(&cnt[row[e]], 1);
    }
}

// ---------------- CSR scan --------------------------------------------------
__global__ void scan_partial(const int* __restrict__ cnt, int* __restrict__ partial) {
    __shared__ int sm[256];
    int i = blockIdx.x * 256 + threadIdx.x;
    int v = (i < NNODES) ? cnt[i] : 0;
    sm[threadIdx.x] = v; __syncthreads();
    for (int s = 128; s > 0; s >>= 1) {
        if (threadIdx.x < s) sm[threadIdx.x] += sm[threadIdx.x + s];
        __syncthreads();
    }
    if (threadIdx.x == 0) partial[blockIdx.x] = sm[0];
}

__global__ void scan_exclusive_small(int* __restrict__ partial, int nb) {
    __shared__ int sm[256];
    int t = threadIdx.x;
    int v = (t < nb) ? partial[t] : 0;
    sm[t] = v; __syncthreads();
    for (int off = 1; off < 256; off <<= 1) {
        int add = (t >= off) ? sm[t - off] : 0;
        __syncthreads();
        sm[t] += add;
        __syncthreads();
    }
    if (t < nb) partial[t] = sm[t] - v;   // exclusive
}

// Writes row_start AND initializes the scatter cursor to the same value.
__global__ void scan_write(const int* __restrict__ cnt, const int* __restrict__ partial,
                           int* __restrict__ row_start, int* __restrict__ cursor) {
    __shared__ int sm[256];
    int t = threadIdx.x;
    int i = blockIdx.x * 256 + t;
    int v = (i < NNODES) ? cnt[i] : 0;
    sm[t] = v; __syncthreads();
    for (int off = 1; off < 256; off <<= 1) {
        int add = (t >= off) ? sm[t - off] : 0;
        __syncthreads();
        sm[t] += add;
        __syncthreads();
    }
    if (i < NNODES) {
        int rs = partial[blockIdx.x] + sm[t] - v;
        row_start[i] = rs;
        cursor[i] = rs;          // absolute cursor for scatter
    }
    if (i == 0) row_start[NNODES] = NEDGES;
}

// scatter: cursor pre-initialized to row_start -> atomicAdd gives CSR slot.
__global__ void scatter_kernel(const int* __restrict__ row, const int* __restrict__ col,
                               const float* __restrict__ val,
                               int* __restrict__ cursor, unsigned int* __restrict__ cv) {
    int e = blockIdx.x * 256 + threadIdx.x;
    if (e < NEDGES) {
        int r = row[e];
        int pos = atomicAdd(&cursor[r], 1);
        unsigned int vb = f2bf(val[e]);
        cv[pos] = (vb << 16) | (unsigned int)col[e];
    }
}

// ---------------- GEMM: S[m][512] = [X@W (ori) | X@W (aug)] bf16 ------------
// Tile 64(m) x 256(n), BK=32, 256 threads = 4 waves (1x4), wave tile 64x64.
// 50 KB LDS + <=170 regs (launch_bounds 256,3) -> 3 blocks/CU resident:
// inter-block TLP hides the barrier drains (the m97 occupancy lesson).
// Distance-1 register prefetch, T14 order (WRITE next / LOAD next+1 /
// COMPUTE cur), raw s_barrier with lgkmcnt-only drain: global loads stay in
// flight across barriers. X read exactly once (nontemporal); Wt re-reads are
// L2-served.
__global__ __launch_bounds__(256, 3)
void gemm_kernel(const float* __restrict__ Xo, const float* __restrict__ Xa,
                 const unsigned short* __restrict__ Wt,
                 unsigned short* __restrict__ S) {
    __shared__ __align__(16) unsigned short As[2][64][40];
    __shared__ __align__(16) unsigned short Bs[2][256][40];
    const int tid = threadIdx.x;
    const int branch = blockIdx.z;
    const float* __restrict__ X = branch ? Xa : Xo;
    const int boff = branch * 256;
    const int m_base = blockIdx.x * 64;
    const int lane = tid & 63, wave = tid >> 6;
    const int wn = wave * 64;                 // wave n-offset; all waves span m 0..63
    const int quad = lane >> 4, r16 = lane & 15;

    f32x4 acc[4][4] = {};

    // staging geometry (256 threads, one A pass + four B passes)
    const int arow = tid >> 2;          // 0..63 (A row, also B row base)
    const int acol = (tid & 3) * 8;     // k-offset 0,8,16,24

    const int gm = m_base + arow;
    const bool va = gm < NNODES;
    const float* pA = &X[(long)gm * DIN + acol];
    const unsigned short* pB0 = &Wt[(long)(arow) * DIN + acol];
    const unsigned short* pB1 = &Wt[(long)(64 + arow) * DIN + acol];
    const unsigned short* pB2 = &Wt[(long)(128 + arow) * DIN + acol];
    const unsigned short* pB3 = &Wt[(long)(192 + arow) * DIN + acol];

    // single prefetch register set (distance-1; TLP via 3 blocks/CU does the rest)
    f32x4 fa0, fa1;
    u32x4 ub0, ub1, ub2, ub3;

#define GEMM_LOAD(K0)                                                          \
    do {                                                                       \
        fa0 = va ? __builtin_nontemporal_load((const f32x4*)(pA + (K0)))       \
                 : (f32x4)0.f;                                                 \
        fa1 = va ? __builtin_nontemporal_load((const f32x4*)(pA + (K0) + 4))   \
                 : (f32x4)0.f;                                                 \
        ub0 = *(const u32x4*)(pB0 + (K0));                                     \
        ub1 = *(const u32x4*)(pB1 + (K0));                                     \
        ub2 = *(const u32x4*)(pB2 + (K0));                                     \
        ub3 = *(const u32x4*)(pB3 + (K0));                                     \
    } while (0)

#define GEMM_WRITE(B)                                                          \
    do {                                                                       \
        usv8 h;                                                                \
        h[0] = f2bf(fa0[0]); h[1] = f2bf(fa0[1]);                              \
        h[2] = f2bf(fa0[2]); h[3] = f2bf(fa0[3]);                              \
        h[4] = f2bf(fa1[0]); h[5] = f2bf(fa1[1]);                              \
        h[6] = f2bf(fa1[2]); h[7] = f2bf(fa1[3]);                              \
        *(usv8*)&As[B][arow][acol] = h;                                        \
        *(u32x4*)&Bs[B][arow][acol] = ub0;                                     \
        *(u32x4*)&Bs[B][64 + arow][acol] = ub1;                                \
        *(u32x4*)&Bs[B][128 + arow][acol] = ub2;                               \
        *(u32x4*)&Bs[B][192 + arow][acol] = ub3;                               \
    } while (0)

#define GEMM_COMPUTE(B)                                                        \
    do {                                                                       \
        short8 a_frag[4], b_frag[4];                                           \
        _Pragma("unroll")                                                      \
        for (int mi = 0; mi < 4; mi++)                                         \
            a_frag[mi] = *(const short8*)&As[B][mi * 16 + r16][quad * 8];      \
        _Pragma("unroll")                                                      \
        for (int ni = 0; ni < 4; ni++)                                         \
            b_frag[ni] = *(const short8*)&Bs[B][wn + ni * 16 + r16][quad * 8]; \
        _Pragma("unroll")                                                      \
        for (int mi = 0; mi < 4; mi++)                                         \
            _Pragma("unroll")                                                  \
            for (int ni = 0; ni < 4; ni++)                                     \
                acc[mi][ni] = __builtin_amdgcn_mfma_f32_16x16x32_bf16(         \
                    a_frag[mi], b_frag[ni], acc[mi][ni], 0, 0, 0);             \
    } while (0)

// lgkmcnt-only drain before barrier: ds ops must be visible, global loads may
// stay in flight (T4). sched_barrier(0) fences hoisting (rule #18).
#define GEMM_BARRIER()                                                         \
    do {                                                                       \
        asm volatile("s_waitcnt lgkmcnt(0)" ::: "memory");                     \
        __builtin_amdgcn_s_barrier();                                          \
        __builtin_amdgcn_sched_barrier(0);                                     \
    } while (0)

    // prologue: tile0 -> buf0; tile1 loads in flight
    GEMM_LOAD(0);
    GEMM_WRITE(0);
    GEMM_LOAD(32);
    GEMM_BARRIER();

    // invariant at top of step t: buf(t&1) = tile t, prefetch set = tile t+1
    #pragma unroll
    for (int t = 0; t < 16; ++t) {
        if (t < 15) GEMM_WRITE((t + 1) & 1);       // vmcnt wait (loads ~done)
        if (t + 2 < 16) GEMM_LOAD((t + 2) * 32);   // issue early: ~1.5-step window
        GEMM_COMPUTE(t & 1);
        if (t < 15) GEMM_BARRIER();
    }

#undef GEMM_LOAD
#undef GEMM_WRITE
#undef GEMM_COMPUTE
#undef GEMM_BARRIER

    // epilogue: bf16 support, interleaved [m][ori 0..255 | aug 256..511]
    // C/D map: col(n)=lane&15, row(m)=quad*4+reg. Plain stores keep S in L2/L3.
    #pragma unroll
    for (int mi = 0; mi < 4; mi++) {
        #pragma unroll
        for (int rr = 0; rr < 4; rr++) {
            int m = m_base + mi * 16 + quad * 4 + rr;
            if (m < NNODES) {
                #pragma unroll
                for (int ni = 0; ni < 4; ni++) {
                    int n = wn + ni * 16 + r16;
                    S[(long)m * 512 + boff + n] = f2bf(acc[mi][ni][rr]);
                }
            }
        }
    }
}

// ---------------- Aggregation: two branch-passes, scalar edge stream --------
__global__ __launch_bounds__(256)
void aggregate_pass(const int* __restrict__ row_start,
                    const unsigned int* __restrict__ cv,
                    const unsigned short* __restrict__ S,
                    const float* __restrict__ bias, float* __restrict__ out,
                    const int half) {
    const int node = __builtin_amdgcn_readfirstlane(blockIdx.x * 4 + (threadIdx.x >> 6));
    if (node >= NNODES) return;
    const int lane = threadIdx.x & 63;
    const int fl = (lane & 31) * 8;                 // feature base 0..248
    const unsigned int sub = lane >> 5;             // 0: even edge, 1: odd edge
    const long soff = (long)half * 256 + fl;
    const int s = row_start[node], e = row_start[node + 1];

    float a0 = 0.f, a1 = 0.f, a2 = 0.f, a3 = 0.f;
    float a4 = 0.f, a5 = 0.f, a6 = 0.f, a7 = 0.f;

#define PLOAD(CW0, CW1, Q)                                                     \
    do {                                                                       \
        unsigned int cw_ = sub ? (CW1) : (CW0);                                \
        Q = *(const usv8*)&S[(long)(cw_ & 0xFFFFu) * 512 + soff];              \
    } while (0)

#define PFMA(CW0, CW1, Q)                                                      \
    do {                                                                       \
        unsigned int cw_ = sub ? (CW1) : (CW0);                                \
        float v = bf2f((unsigned short)(cw_ >> 16));                           \
        a0 = fmaf(v, bf2f((Q)[0]), a0); a1 = fmaf(v, bf2f((Q)[1]), a1);        \
        a2 = fmaf(v, bf2f((Q)[2]), a2); a3 = fmaf(v, bf2f((Q)[3]), a3);        \
        a4 = fmaf(v, bf2f((Q)[4]), a4); a5 = fmaf(v, bf2f((Q)[5]), a5);        \
        a6 = fmaf(v, bf2f((Q)[6]), a6); a7 = fmaf(v, bf2f((Q)[7]), a7);        \
    } while (0)

#define LOADG(C0, C1, C2, C3, C4, C5, C6, C7, Q0, Q1, Q2, Q3, I)               \
    do {                                                                       \
        C0 = cv[(I)];     C1 = cv[(I) + 1]; C2 = cv[(I) + 2]; C3 = cv[(I) + 3];\
        C4 = cv[(I) + 4]; C5 = cv[(I) + 5]; C6 = cv[(I) + 6]; C7 = cv[(I) + 7];\
        PLOAD(C0, C1, Q0); PLOAD(C2, C3, Q1);                                  \
        PLOAD(C4, C5, Q2); PLOAD(C6, C7, Q3);                                  \
    } while (0)

#define FMAG(C0, C1, C2, C3, C4, C5, C6, C7, Q0, Q1, Q2, Q3)                   \
    do {                                                                       \
        PFMA(C0, C1, Q0); PFMA(C2, C3, Q1);                                    \
        PFMA(C4, C5, Q2); PFMA(C6, C7, Q3);                                    \
    } while (0)

    unsigned int c0, c1, c2, c3, c4, c5, c6, c7;
    unsigned int d0, d1, d2, d3, d4, d5, d6, d7;
    usv8 qa0, qa1, qa2, qa3, qb0, qb1, qb2, qb3;

    int idx = s;
    int r = (e - s) >> 3;           // full 8-edge groups
    if (r > 0) {
        LOADG(c0, c1, c2, c3, c4, c5, c6, c7, qa0, qa1, qa2, qa3, idx); idx += 8; r--;
        while (r >= 2) {
            LOADG(d0, d1, d2, d3, d4, d5, d6, d7, qb0, qb1, qb2, qb3, idx); idx += 8;
            FMAG(c0, c1, c2, c3, c4, c5, c6, c7, qa0, qa1, qa2, qa3);
            LOADG(c0, c1, c2, c3, c4, c5, c6, c7, qa0, qa1, qa2, qa3, idx); idx += 8;
            FMAG(d0, d1, d2, d3, d4, d5, d6, d7, qb0, qb1, qb2, qb3);
            r -= 2;
        }
        if (r == 1) {
            LOADG(d0, d1, d2, d3, d4, d5, d6, d7, qb0, qb1, qb2, qb3, idx); idx += 8;
            FMAG(c0, c1, c2, c3, c4, c5, c6, c7, qa0, qa1, qa2, qa3);
            FMAG(d0, d1, d2, d3, d4, d5, d6, d7, qb0, qb1, qb2, qb3);
        } else {
            FMAG(c0, c1, c2, c3, c4, c5, c6, c7, qa0, qa1, qa2, qa3);
        }
    }
    // pair tail
    for (; idx + 2 <= e; idx += 2) {
        unsigned int w0 = cv[idx], w1 = cv[idx + 1];
        usv8 q;
        PLOAD(w0, w1, q);
        PFMA(w0, w1, q);
    }
    // final odd edge: only the even half-wave contributes
    if (idx < e) {
        unsigned int w = cv[idx];
        usv8 q = *(const usv8*)&S[(long)(w & 0xFFFFu) * 512 + soff];
        float v = sub ? 0.f : bf2f((unsigned short)(w >> 16));
        a0 = fmaf(v, bf2f(q[0]), a0); a1 = fmaf(v, bf2f(q[1]), a1);
        a2 = fmaf(v, bf2f(q[2]), a2); a3 = fmaf(v, bf2f(q[3]), a3);
        a4 = fmaf(v, bf2f(q[4]), a4); a5 = fmaf(v, bf2f(q[5]), a5);
        a6 = fmaf(v, bf2f(q[6]), a6); a7 = fmaf(v, bf2f(q[7]), a7);
    }

#undef PLOAD
#undef PFMA
#undef LOADG
#undef FMAG

    // combine even/odd halves: lane l += lane l^32
    a0 += __shfl_xor(a0, 32); a1 += __shfl_xor(a1, 32);
    a2 += __shfl_xor(a2, 32); a3 += __shfl_xor(a3, 32);
    a4 += __shfl_xor(a4, 32); a5 += __shfl_xor(a5, 32);
    a6 += __shfl_xor(a6, 32); a7 += __shfl_xor(a7, 32);

    if (lane < 32) {
        f32x4 b0 = *(const f32x4*)&bias[fl];
        f32x4 b1 = *(const f32x4*)&bias[fl + 4];
        long o = (long)half * NNODES * FOUT + (long)node * FOUT + fl;
        f32x4 r0, r1;
        r0[0] = fmaxf(a0 + b0[0], 0.f); r0[1] = fmaxf(a1 + b0[1], 0.f);
        r0[2] = fmaxf(a2 + b0[2], 0.f); r0[3] = fmaxf(a3 + b0[3], 0.f);
        r1[0] = fmaxf(a4 + b1[0], 0.f); r1[1] = fmaxf(a5 + b1[1], 0.f);
        r1[2] = fmaxf(a6 + b1[2], 0.f); r1[3] = fmaxf(a7 + b1[3], 0.f);
        __builtin_nontemporal_store(r0, (f32x4*)&out[o]);
        __builtin_nontemporal_store(r1, (f32x4*)&out[o + 4]);
    }
}

// ---------------- launch ----------------------------------------------------
extern "C" void kernel_launch(void* const* d_in, const int* in_sizes, int n_in,
                              void* d_out, int out_size, void* d_ws, size_t ws_size,
                              hipStream_t stream) {
    const float* Xo   = (const float*)d_in[0];
    const float* Xa   = (const float*)d_in[1];
    const int*   erow = (const int*)d_in[2];
    const int*   ecol = (const int*)d_in[3];
    const float* eval_= (const float*)d_in[4];
    const float* W    = (const float*)d_in[5];
    const float* bias = (const float*)d_in[6];
    float* out = (float*)d_out;

    char* ws = (char*)d_ws;
    // workspace layout (~55.06 MB total)
    unsigned short* S         = (unsigned short*)(ws);                 // 51,200,000 B
    unsigned short* Wt        = (unsigned short*)(ws + 51200000);      //    262,144 B
    int*            cnt       = (int*)(ws + 51462144);                 //    200,000 B (hist, then cursor)
    int*            row_start = (int*)(ws + 51662144);                 //    200,064 B (50001 ints)
    int*            partial   = (int*)(ws + 51862208);                 //      1,024 B
    unsigned int*   cv        = (unsigned int*)(ws + 51863232);        //  3,200,000 B

    (void)in_sizes; (void)n_in; (void)out_size; (void)ws_size;

    hipMemsetAsync(cnt, 0, 200000, stream);
    prep_kernel<<<3637, 256, 0, stream>>>(W, Wt, erow, cnt);
    scan_partial<<<196, 256, 0, stream>>>(cnt, partial);
    scan_exclusive_small<<<1, 256, 0, stream>>>(partial, 196);
    scan_write<<<196, 256, 0, stream>>>(cnt, partial, row_start, cnt);
    scatter_kernel<<<3125, 256, 0, stream>>>(erow, ecol, eval_, cnt, cv);

    dim3 gg(782, 1, 2);
    gemm_kernel<<<gg, 256, 0, stream>>>(Xo, Xa, Wt, S);

    aggregate_pass<<<12500, 256, 0, stream>>>(row_start, cv, S, bias, out, 0);
    aggregate_pass<<<12500, 256, 0, stream>>>(row_start, cv, S, bias, out, 1);
}

// Round 7
// 482.056 us; speedup vs baseline: 1.0057x; 1.0057x over previous
//
#include <hip/hip_runtime.h>
#include <hip/hip_bf16.h>

// Problem constants (fixed by reference setup_inputs)
#define NNODES 50000
#define NEDGES 800000
#define DIN    512
#define FOUT   256

typedef __attribute__((ext_vector_type(8))) short short8;
typedef __attribute__((ext_vector_type(4))) float f32x4;
typedef __attribute__((ext_vector_type(4))) unsigned int u32x4;
typedef __attribute__((ext_vector_type(4))) unsigned short usv4;
typedef __attribute__((ext_vector_type(8))) unsigned short usv8;

static __device__ __forceinline__ unsigned short f2bf(float f) {
    unsigned int u = __float_as_uint(f);
    u += 0x7FFF + ((u >> 16) & 1);   // round-to-nearest-even
    return (unsigned short)(u >> 16);
}
static __device__ __forceinline__ float bf2f(unsigned short h) {
    return __uint_as_float(((unsigned int)h) << 16);
}

// async global->LDS, 16B per lane: dest = wave-uniform lds base + lane*16,
// source = per-lane global address (guide §5; m97/m193 pattern).
static __device__ __forceinline__ void gload_lds16(const void* g, void* l) {
    __builtin_amdgcn_global_load_lds(
        (const __attribute__((address_space(1))) unsigned int*)g,
        (__attribute__((address_space(3))) unsigned int*)l, 16, 0, 0);
}

// ---------------- prep: W^T convert (blocks 0..511) + edge hist (512..) -----
__global__ void prep_kernel(const float* __restrict__ W, unsigned short* __restrict__ Wt,
                            const int* __restrict__ row, int* __restrict__ cnt) {
    int b = blockIdx.x;
    if (b < 512) {
        int o = b * 256 + threadIdx.x;           // 131072 total
        int n = o >> 9, k = o & 511;
        Wt[o] = f2bf(W[k * FOUT + n]);
    } else {
        int e = (b - 512) * 256 + threadIdx.x;
        if (e < NEDGES) atomicAdd(&cnt[row[e]], 1);
    }
}

// ---------------- CSR scan --------------------------------------------------
__global__ void scan_partial(const int* __restrict__ cnt, int* __restrict__ partial) {
    __shared__ int sm[256];
    int i = blockIdx.x * 256 + threadIdx.x;
    int v = (i < NNODES) ? cnt[i] : 0;
    sm[threadIdx.x] = v; __syncthreads();
    for (int s = 128; s > 0; s >>= 1) {
        if (threadIdx.x < s) sm[threadIdx.x] += sm[threadIdx.x + s];
        __syncthreads();
    }
    if (threadIdx.x == 0) partial[blockIdx.x] = sm[0];
}

__global__ void scan_exclusive_small(int* __restrict__ partial, int nb) {
    __shared__ int sm[256];
    int t = threadIdx.x;
    int v = (t < nb) ? partial[t] : 0;
    sm[t] = v; __syncthreads();
    for (int off = 1; off < 256; off <<= 1) {
        int add = (t >= off) ? sm[t - off] : 0;
        __syncthreads();
        sm[t] += add;
        __syncthreads();
    }
    if (t < nb) partial[t] = sm[t] - v;   // exclusive
}

// Writes row_start AND initializes the scatter cursor to the same value.
__global__ void scan_write(const int* __restrict__ cnt, const int* __restrict__ partial,
                           int* __restrict__ row_start, int* __restrict__ cursor) {
    __shared__ int sm[256];
    int t = threadIdx.x;
    int i = blockIdx.x * 256 + t;
    int v = (i < NNODES) ? cnt[i] : 0;
    sm[t] = v; __syncthreads();
    for (int off = 1; off < 256; off <<= 1) {
        int add = (t >= off) ? sm[t - off] : 0;
        __syncthreads();
        sm[t] += add;
        __syncthreads();
    }
    if (i < NNODES) {
        int rs = partial[blockIdx.x] + sm[t] - v;
        row_start[i] = rs;
        cursor[i] = rs;          // absolute cursor for scatter
    }
    if (i == 0) row_start[NNODES] = NEDGES;
}

// scatter: cursor pre-initialized to row_start -> atomicAdd gives CSR slot.
__global__ void scatter_kernel(const int* __restrict__ row, const int* __restrict__ col,
                               const float* __restrict__ val,
                               int* __restrict__ cursor, unsigned int* __restrict__ cv) {
    int e = blockIdx.x * 256 + threadIdx.x;
    if (e < NEDGES) {
        int r = row[e];
        int pos = atomicAdd(&cursor[r], 1);
        unsigned int vb = f2bf(val[e]);
        cv[pos] = (vb << 16) | (unsigned int)col[e];
    }
}

// ---------------- GEMM: S[m][512] = [X@W (ori) | X@W (aug)] bf16 ------------
// 128(m) x 256(n) block, BK=32, 512 threads = 8 waves (2x4), wave tile 64x64.
// B (bf16 Wt) staged via global_load_lds width-16 into LINEAR Bs[256][32]
// (fire-and-forget DMA, no VGPR round-trip); A (f32->bf16 cvt) reg-staged
// dist-2 into padded As[128][40]. Counted vmcnt(2) before each barrier: only
// next tile's B-gloads drained, A loads stay in flight across barriers (T4).
__global__ __launch_bounds__(512, 2)
void gemm_kernel(const float* __restrict__ Xo, const float* __restrict__ Xa,
                 const unsigned short* __restrict__ Wt,
                 unsigned short* __restrict__ S) {
    __shared__ __align__(16) unsigned short As[2][128][40];
    __shared__ __align__(16) unsigned short Bs[2][256][32];   // linear: gload_lds dest
    const int tid = threadIdx.x;
    const int branch = blockIdx.z;
    const float* __restrict__ X = branch ? Xa : Xo;
    const int boff = branch * 256;
    const int m_base = blockIdx.x * 128;
    const int lane = tid & 63, wave = tid >> 6;
    const int wm = (wave >> 2) * 64, wn = (wave & 3) * 64;
    const int quad = lane >> 4, r16 = lane & 15;

    f32x4 acc[4][4] = {};

    // A staging geometry (512 threads, one pass): row tid>>2, k-chunk (tid&3)*8
    const int arow = tid >> 2;          // 0..127
    const int acol = (tid & 3) * 8;     // 0,8,16,24
    const int gm = m_base + arow;
    const bool va = gm < NNODES;
    const float* pA = &X[(long)gm * DIN + acol];

    // B gload geometry: wave w covers rows 32w..32w+31 (2 issues of 16 rows).
    // lane -> row offset lane>>2, k-slot lane&3 (16B each).
    const int brow0 = wave * 32 + (lane >> 2);
    const unsigned short* pB0 = &Wt[(long)brow0 * DIN + (lane & 3) * 8];
    const unsigned short* pB1 = &Wt[(long)(brow0 + 16) * DIN + (lane & 3) * 8];

    // two static A prefetch sets (dist-2; rule #20: no runtime indexing)
    f32x4 fa0A, fa1A, fa0B, fa1B;

#define GEMM_GLOADB(T, B)                                                      \
    do {                                                                       \
        const int k0_ = (T) * 32;                                              \
        gload_lds16(pB0 + k0_, &Bs[B][wave * 32][0]);                          \
        gload_lds16(pB1 + k0_, &Bs[B][wave * 32 + 16][0]);                     \
    } while (0)

#define GEMM_LOADA(SET, K0)                                                    \
    do {                                                                       \
        fa0##SET = va ? __builtin_nontemporal_load((const f32x4*)(pA + (K0)))  \
                      : (f32x4)0.f;                                            \
        fa1##SET = va ? __builtin_nontemporal_load((const f32x4*)(pA + (K0) + 4))\
                      : (f32x4)0.f;                                            \
    } while (0)

#define GEMM_WRITEA(SET, B)                                                    \
    do {                                                                       \
        usv8 h;                                                                \
        h[0] = f2bf(fa0##SET[0]); h[1] = f2bf(fa0##SET[1]);                    \
        h[2] = f2bf(fa0##SET[2]); h[3] = f2bf(fa0##SET[3]);                    \
        h[4] = f2bf(fa1##SET[0]); h[5] = f2bf(fa1##SET[1]);                    \
        h[6] = f2bf(fa1##SET[2]); h[7] = f2bf(fa1##SET[3]);                    \
        *(usv8*)&As[B][arow][acol] = h;                                        \
    } while (0)

#define GEMM_COMPUTE(B)                                                        \
    do {                                                                       \
        short8 a_frag[4], b_frag[4];                                           \
        _Pragma("unroll")                                                      \
        for (int mi = 0; mi < 4; mi++)                                         \
            a_frag[mi] = *(const short8*)&As[B][wm + mi * 16 + r16][quad * 8]; \
        _Pragma("unroll")                                                      \
        for (int ni = 0; ni < 4; ni++)                                         \
            b_frag[ni] = *(const short8*)&Bs[B][wn + ni * 16 + r16][quad * 8]; \
        _Pragma("unroll")                                                      \
        for (int mi = 0; mi < 4; mi++)                                         \
            _Pragma("unroll")                                                  \
            for (int ni = 0; ni < 4; ni++)                                     \
                acc[mi][ni] = __builtin_amdgcn_mfma_f32_16x16x32_bf16(         \
                    a_frag[mi], b_frag[ni], acc[mi][ni], 0, 0, 0);             \
    } while (0)

    // ---- prologue: tile0 staged, tile1 A-loads + B-gloads in flight ----
    GEMM_LOADA(A, 0);                 // A tile0 -> set A
    GEMM_GLOADB(0, 0);                // B tile0 -> buf0 (DMA)
    GEMM_LOADA(B, 32);                // A tile1 -> set B
    GEMM_WRITEA(A, 0);                // waits A tile0 loads (compiler vmcnt)
    asm volatile("s_waitcnt vmcnt(2)" ::: "memory");   // B tile0 in LDS; A tile1 in flight
    asm volatile("s_waitcnt lgkmcnt(0)" ::: "memory");
    __builtin_amdgcn_s_barrier();
    __builtin_amdgcn_sched_barrier(0);

    // invariant at top of step t: buf(t&1) = tile t; A set parity (t+1)&1 = tile t+1
    #pragma unroll
    for (int t = 0; t < 16; ++t) {
        if (t + 1 < 16) GEMM_GLOADB(t + 1, (t + 1) & 1);
        __builtin_amdgcn_sched_barrier(0);   // pin gloads before A loads (vmcnt order)
        if (t + 1 < 16) {
            if (((t + 1) & 1) == 0) GEMM_WRITEA(A, 0); else GEMM_WRITEA(B, 1);
        }
        if (t + 2 < 16) {
            if ((t & 1) == 0) GEMM_LOADA(A, (t + 2) * 32); else GEMM_LOADA(B, (t + 2) * 32);
        }
        GEMM_COMPUTE(t & 1);
        if (t < 15) {
            if (t <= 13) asm volatile("s_waitcnt vmcnt(2)" ::: "memory");  // drain B gloads only
            else         asm volatile("s_waitcnt vmcnt(0)" ::: "memory");  // t=14: nothing else in flight
            asm volatile("s_waitcnt lgkmcnt(0)" ::: "memory");
            __builtin_amdgcn_s_barrier();
            __builtin_amdgcn_sched_barrier(0);
        }
    }

#undef GEMM_GLOADB
#undef GEMM_LOADA
#undef GEMM_WRITEA
#undef GEMM_COMPUTE

    // epilogue: bf16 support, interleaved [m][ori 0..255 | aug 256..511]
    // C/D map: col(n)=lane&15, row(m)=quad*4+reg. Plain stores keep S in L2/L3.
    #pragma unroll
    for (int mi = 0; mi < 4; mi++) {
        #pragma unroll
        for (int rr = 0; rr < 4; rr++) {
            int m = m_base + wm + mi * 16 + quad * 4 + rr;
            if (m < NNODES) {
                #pragma unroll
                for (int ni = 0; ni < 4; ni++) {
                    int n = wn + ni * 16 + r16;
                    S[(long)m * 512 + boff + n] = f2bf(acc[mi][ni][rr]);
                }
            }
        }
    }
}

// ---------------- Aggregation: two branch-passes, scalar edge stream --------
__global__ __launch_bounds__(256)
void aggregate_pass(const int* __restrict__ row_start,
                    const unsigned int* __restrict__ cv,
                    const unsigned short* __restrict__ S,
                    const float* __restrict__ bias, float* __restrict__ out,
                    const int half) {
    const int node = __builtin_amdgcn_readfirstlane(blockIdx.x * 4 + (threadIdx.x >> 6));
    if (node >= NNODES) return;
    const int lane = threadIdx.x & 63;
    const int fl = (lane & 31) * 8;                 // feature base 0..248
    const unsigned int sub = lane >> 5;             // 0: even edge, 1: odd edge
    const long soff = (long)half * 256 + fl;
    const int s = row_start[node], e = row_start[node + 1];

    float a0 = 0.f, a1 = 0.f, a2 = 0.f, a3 = 0.f;
    float a4 = 0.f, a5 = 0.f, a6 = 0.f, a7 = 0.f;

#define PLOAD(CW0, CW1, Q)                                                     \
    do {                                                                       \
        unsigned int cw_ = sub ? (CW1) : (CW0);                                \
        Q = *(const usv8*)&S[(long)(cw_ & 0xFFFFu) * 512 + soff];              \
    } while (0)

#define PFMA(CW0, CW1, Q)                                                      \
    do {                                                                       \
        unsigned int cw_ = sub ? (CW1) : (CW0);                                \
        float v = bf2f((unsigned short)(cw_ >> 16));                           \
        a0 = fmaf(v, bf2f((Q)[0]), a0); a1 = fmaf(v, bf2f((Q)[1]), a1);        \
        a2 = fmaf(v, bf2f((Q)[2]), a2); a3 = fmaf(v, bf2f((Q)[3]), a3);        \
        a4 = fmaf(v, bf2f((Q)[4]), a4); a5 = fmaf(v, bf2f((Q)[5]), a5);        \
        a6 = fmaf(v, bf2f((Q)[6]), a6); a7 = fmaf(v, bf2f((Q)[7]), a7);        \
    } while (0)

#define LOADG(C0, C1, C2, C3, C4, C5, C6, C7, Q0, Q1, Q2, Q3, I)               \
    do {                                                                       \
        C0 = cv[(I)];     C1 = cv[(I) + 1]; C2 = cv[(I) + 2]; C3 = cv[(I) + 3];\
        C4 = cv[(I) + 4]; C5 = cv[(I) + 5]; C6 = cv[(I) + 6]; C7 = cv[(I) + 7];\
        PLOAD(C0, C1, Q0); PLOAD(C2, C3, Q1);                                  \
        PLOAD(C4, C5, Q2); PLOAD(C6, C7, Q3);                                  \
    } while (0)

#define FMAG(C0, C1, C2, C3, C4, C5, C6, C7, Q0, Q1, Q2, Q3)                   \
    do {                                                                       \
        PFMA(C0, C1, Q0); PFMA(C2, C3, Q1);                                    \
        PFMA(C4, C5, Q2); PFMA(C6, C7, Q3);                                    \
    } while (0)

    unsigned int c0, c1, c2, c3, c4, c5, c6, c7;
    unsigned int d0, d1, d2, d3, d4, d5, d6, d7;
    usv8 qa0, qa1, qa2, qa3, qb0, qb1, qb2, qb3;

    int idx = s;
    int r = (e - s) >> 3;           // full 8-edge groups
    if (r > 0) {
        LOADG(c0, c1, c2, c3, c4, c5, c6, c7, qa0, qa1, qa2, qa3, idx); idx += 8; r--;
        while (r >= 2) {
            LOADG(d0, d1, d2, d3, d4, d5, d6, d7, qb0, qb1, qb2, qb3, idx); idx += 8;
            FMAG(c0, c1, c2, c3, c4, c5, c6, c7, qa0, qa1, qa2, qa3);
            LOADG(c0, c1, c2, c3, c4, c5, c6, c7, qa0, qa1, qa2, qa3, idx); idx += 8;
            FMAG(d0, d1, d2, d3, d4, d5, d6, d7, qb0, qb1, qb2, qb3);
            r -= 2;
        }
        if (r == 1) {
            LOADG(d0, d1, d2, d3, d4, d5, d6, d7, qb0, qb1, qb2, qb3, idx); idx += 8;
            FMAG(c0, c1, c2, c3, c4, c5, c6, c7, qa0, qa1, qa2, qa3);
            FMAG(d0, d1, d2, d3, d4, d5, d6, d7, qb0, qb1, qb2, qb3);
        } else {
            FMAG(c0, c1, c2, c3, c4, c5, c6, c7, qa0, qa1, qa2, qa3);
        }
    }
    // pair tail
    for (; idx + 2 <= e; idx += 2) {
        unsigned int w0 = cv[idx], w1 = cv[idx + 1];
        usv8 q;
        PLOAD(w0, w1, q);
        PFMA(w0, w1, q);
    }
    // final odd edge: only the even half-wave contributes
    if (idx < e) {
        unsigned int w = cv[idx];
        usv8 q = *(const usv8*)&S[(long)(w & 0xFFFFu) * 512 + soff];
        float v = sub ? 0.f : bf2f((unsigned short)(w >> 16));
        a0 = fmaf(v, bf2f(q[0]), a0); a1 = fmaf(v, bf2f(q[1]), a1);
        a2 = fmaf(v, bf2f(q[2]), a2); a3 = fmaf(v, bf2f(q[3]), a3);
        a4 = fmaf(v, bf2f(q[4]), a4); a5 = fmaf(v, bf2f(q[5]), a5);
        a6 = fmaf(v, bf2f(q[6]), a6); a7 = fmaf(v, bf2f(q[7]), a7);
    }

#undef PLOAD
#undef PFMA
#undef LOADG
#undef FMAG

    // combine even/odd halves: lane l += lane l^32
    a0 += __shfl_xor(a0, 32); a1 += __shfl_xor(a1, 32);
    a2 += __shfl_xor(a2, 32); a3 += __shfl_xor(a3, 32);
    a4 += __shfl_xor(a4, 32); a5 += __shfl_xor(a5, 32);
    a6 += __shfl_xor(a6, 32); a7 += __shfl_xor(a7, 32);

    if (lane < 32) {
        f32x4 b0 = *(const f32x4*)&bias[fl];
        f32x4 b1 = *(const f32x4*)&bias[fl + 4];
        long o = (long)half * NNODES * FOUT + (long)node * FOUT + fl;
        f32x4 r0, r1;
        r0[0] = fmaxf(a0 + b0[0], 0.f); r0[1] = fmaxf(a1 + b0[1], 0.f);
        r0[2] = fmaxf(a2 + b0[2], 0.f); r0[3] = fmaxf(a3 + b0[3], 0.f);
        r1[0] = fmaxf(a4 + b1[0], 0.f); r1[1] = fmaxf(a5 + b1[1], 0.f);
        r1[2] = fmaxf(a6 + b1[2], 0.f); r1[3] = fmaxf(a7 + b1[3], 0.f);
        __builtin_nontemporal_store(r0, (f32x4*)&out[o]);
        __builtin_nontemporal_store(r1, (f32x4*)&out[o + 4]);
    }
}

// ---------------- launch ----------------------------------------------------
extern "C" void kernel_launch(void* const* d_in, const int* in_sizes, int n_in,
                              void* d_out, int out_size, void* d_ws, size_t ws_size,
                              hipStream_t stream) {
    const float* Xo   = (const float*)d_in[0];
    const float* Xa   = (const float*)d_in[1];
    const int*   erow = (const int*)d_in[2];
    const int*   ecol = (const int*)d_in[3];
    const float* eval_= (const float*)d_in[4];
    const float* W    = (const float*)d_in[5];
    const float* bias = (const float*)d_in[6];
    float* out = (float*)d_out;

    char* ws = (char*)d_ws;
    // workspace layout (~55.06 MB total)
    unsigned short* S         = (unsigned short*)(ws);                 // 51,200,000 B
    unsigned short* Wt        = (unsigned short*)(ws + 51200000);      //    262,144 B
    int*            cnt       = (int*)(ws + 51462144);                 //    200,000 B (hist, then cursor)
    int*            row_start = (int*)(ws + 51662144);                 //    200,064 B (50001 ints)
    int*            partial   = (int*)(ws + 51862208);                 //      1,024 B
    unsigned int*   cv        = (unsigned int*)(ws + 51863232);        //  3,200,000 B

    (void)in_sizes; (void)n_in; (void)out_size; (void)ws_size;

    hipMemsetAsync(cnt, 0, 200000, stream);
    prep_kernel<<<3637, 256, 0, stream>>>(W, Wt, erow, cnt);
    scan_partial<<<196, 256, 0, stream>>>(cnt, partial);
    scan_exclusive_small<<<1, 256, 0, stream>>>(partial, 196);
    scan_write<<<196, 256, 0, stream>>>(cnt, partial, row_start, cnt);
    scatter_kernel<<<3125, 256, 0, stream>>>(erow, ecol, eval_, cnt, cv);

    dim3 gg(391, 1, 2);
    gemm_kernel<<<gg, 512, 0, stream>>>(Xo, Xa, Wt, S);

    aggregate_pass<<<12500, 256, 0, stream>>>(row_start, cv, S, bias, out, 0);
    aggregate_pass<<<12500, 256, 0, stream>>>(row_start, cv, S, bias, out, 1);
}